// Round 4
// baseline (306.294 us; speedup 1.0000x reference)
//
#include <hip/hip_runtime.h>
#include <cstdint>

#define N_NODES 50000
#define TILE 32
#define NBLK ((N_NODES + TILE - 1) / TILE)  // 1563

// fragment / accumulator vector types (gfx950 mfma bf16 builtins take v8 bf16)
typedef __bf16 bf16x8 __attribute__((ext_vector_type(8)));
typedef unsigned short ushort8_t __attribute__((ext_vector_type(8)));
typedef float f32x4 __attribute__((ext_vector_type(4)));
typedef float f32x2 __attribute__((ext_vector_type(2)));

__device__ __forceinline__ unsigned short f2bf(float x) {
  // native RNE convert: single v_cvt op (vs 3-4 VALU ops for manual bit math)
  return __builtin_bit_cast(unsigned short, (__bf16)x);
}

__device__ __forceinline__ float fast_silu(float x) {
  return x / (1.0f + __expf(-x));
}

__device__ __forceinline__ f32x4 ld4(const float* p) {
  return *(const f32x4*)p;  // callers guarantee 16B alignment
}

// ---------------------------------------------------------------------------
// Prologue: shuffle all 8 weight matrices (fp32 [f][g], 128x128) into
// B-fragment-ordered bf16 atoms in d_ws.
// Atom (c in 0..7 coltile, kt in 0..3 kstep, lane in 0..63) holds 8 bf16:
//   W[k0+j][g],  g = (lane&15)+16c,  k0 = 32kt + (lane>>4)*8,  j=0..7
// ---------------------------------------------------------------------------
__global__ __launch_bounds__(256) void prep_weights(
    const float* __restrict__ Wq1, const float* __restrict__ Wq2,
    const float* __restrict__ WT1, const float* __restrict__ WT2,
    const float* __restrict__ WT3, const float* __restrict__ Ws1,
    const float* __restrict__ Ws2, const float* __restrict__ Wv,
    unsigned short* __restrict__ ws) {
  int tid = blockIdx.x * 256 + threadIdx.x;
  int w = tid >> 11;          // which weight (0..7), 2048 atoms each
  int rest = tid & 2047;      // atom index = (c*4+kt)*64 + lane
  int c = rest >> 8;
  int kt = (rest >> 6) & 3;
  int lane = rest & 63;
  int g = (lane & 15) + 16 * c;
  int k0 = kt * 32 + (lane >> 4) * 8;
  const float* srcs[8] = {Wq1, Wq2, WT1, WT2, WT3, Ws1, Ws2, Wv};
  const float* src = srcs[w];
  union { unsigned short u[8]; uint4 v; } o;
#pragma unroll
  for (int j = 0; j < 8; ++j) o.u[j] = f2bf(src[(k0 + j) * 128 + g]);
  *(uint4*)(ws + (size_t)w * 16384 + (size_t)rest * 8) = o.v;
}

// ---------------------------------------------------------------------------
// B-fragment batch: all 8 fragments for one weight, one wave's col pair.
// Loaded as a unit so the loads can be issued ACROSS a barrier / during the
// previous stage's epilogue (compiler cannot hoist loads over __syncthreads
// itself — explicit prefetch is the only way to keep them in flight).
// ---------------------------------------------------------------------------
__device__ __forceinline__ bf16x8 ldB(const unsigned short* __restrict__ wg,
                                      int c, int kt, int lane) {
  return __builtin_bit_cast(
      bf16x8, *(const ushort8_t*)(wg + (((c * 4 + kt) * 64 + lane)) * 8));
}

struct BF { bf16x8 v[2][4]; };

__device__ __forceinline__ BF loadB8(const unsigned short* __restrict__ wg,
                                     int lane, int cb) {
  BF r;
#pragma unroll
  for (int cc = 0; cc < 2; ++cc)
#pragma unroll
    for (int kt = 0; kt < 4; ++kt) r.v[cc][kt] = ldB(wg, cb + cc, kt, lane);
  return r;
}

__device__ __forceinline__ bf16x8 ldA(const unsigned short* __restrict__ sA,
                                      int row, int k0) {
  return __builtin_bit_cast(bf16x8, *(const ushort8_t*)(sA + row * 136 + k0));
}

// GEMM with preloaded B: Y[32x128] = A[32x128] @ W[128x128], 4 waves/block.
__device__ __forceinline__ void gemm16p(const unsigned short* __restrict__ sA,
                                        const BF& B, int lane, f32x4 acc[2][2]) {
  const int m = lane & 15, q = lane >> 4;
  bf16x8 a0[4], a1[4];
#pragma unroll
  for (int kt = 0; kt < 4; ++kt) {
    const int k0 = q * 8 + kt * 32;
    a0[kt] = ldA(sA, m, k0);
    a1[kt] = ldA(sA, m + 16, k0);
  }
  const f32x4 vzero = {0.f, 0.f, 0.f, 0.f};
#pragma unroll
  for (int rt = 0; rt < 2; ++rt)
#pragma unroll
    for (int cc = 0; cc < 2; ++cc) acc[rt][cc] = vzero;
#pragma unroll
  for (int kt = 0; kt < 4; ++kt)
#pragma unroll
    for (int cc = 0; cc < 2; ++cc) {
      acc[0][cc] = __builtin_amdgcn_mfma_f32_16x16x32_bf16(a0[kt], B.v[cc][kt], acc[0][cc], 0, 0, 0);
      acc[1][cc] = __builtin_amdgcn_mfma_f32_16x16x32_bf16(a1[kt], B.v[cc][kt], acc[1][cc], 0, 0, 0);
    }
}

// 3-channel GEMM sharing preloaded B fragments.
__device__ __forceinline__ void gemm3p(const unsigned short* __restrict__ s0,
                                       const unsigned short* __restrict__ s1,
                                       const unsigned short* __restrict__ s2,
                                       const BF& B, int lane,
                                       f32x4 A1[2][2], f32x4 A2[2][2],
                                       f32x4 A3[2][2]) {
  const int m = lane & 15, q = lane >> 4;
  const f32x4 vzero = {0.f, 0.f, 0.f, 0.f};
#pragma unroll
  for (int rt = 0; rt < 2; ++rt)
#pragma unroll
    for (int cc = 0; cc < 2; ++cc) {
      A1[rt][cc] = vzero; A2[rt][cc] = vzero; A3[rt][cc] = vzero;
    }
#pragma unroll
  for (int kt = 0; kt < 4; ++kt) {
    const int k0 = q * 8 + kt * 32;
    bf16x8 a00 = ldA(s0, m, k0);
    bf16x8 a01 = ldA(s0, m + 16, k0);
    bf16x8 a10 = ldA(s1, m, k0);
    bf16x8 a11 = ldA(s1, m + 16, k0);
    bf16x8 a20 = ldA(s2, m, k0);
    bf16x8 a21 = ldA(s2, m + 16, k0);
#pragma unroll
    for (int cc = 0; cc < 2; ++cc) {
      A1[0][cc] = __builtin_amdgcn_mfma_f32_16x16x32_bf16(a00, B.v[cc][kt], A1[0][cc], 0, 0, 0);
      A1[1][cc] = __builtin_amdgcn_mfma_f32_16x16x32_bf16(a01, B.v[cc][kt], A1[1][cc], 0, 0, 0);
      A2[0][cc] = __builtin_amdgcn_mfma_f32_16x16x32_bf16(a10, B.v[cc][kt], A2[0][cc], 0, 0, 0);
      A2[1][cc] = __builtin_amdgcn_mfma_f32_16x16x32_bf16(a11, B.v[cc][kt], A2[1][cc], 0, 0, 0);
      A3[0][cc] = __builtin_amdgcn_mfma_f32_16x16x32_bf16(a20, B.v[cc][kt], A3[0][cc], 0, 0, 0);
      A3[1][cc] = __builtin_amdgcn_mfma_f32_16x16x32_bf16(a21, B.v[cc][kt], A3[1][cc], 0, 0, 0);
    }
  }
}

// ---------------------------------------------------------------------------
// sT row layout (stride 56 f32, all float4-aligned groups):
//  [ 0.. 3] T0, T1x, T1y, T1z
//  [ 4..12] T2 raw [i*3+c] (pad 13..15)
//  [16..21] q2 pairs (00,01,02,11,12,22)        (pad 22..23)
//  [24..33] c3 multisets (10)                   (pad 34..35)
//  [36..53] d3[i][pair] (18)                    (pad 54..55)
// Coefficient reads are ds_read_b128: ~120 per thread vs ~400 b32 before.
// ---------------------------------------------------------------------------
#define ST_STRIDE 56

// Fused main kernel. 5 barriers (H/G double-buffered in sXmain2).
// __launch_bounds__(256,2): R1 proved capping below the ~112-float live
// accumulator state spills ~1GB. Occupancy pinned at 2 waves/SIMD by the
// unified VGPR+AGPR total (R2/R3 evidence: 128 arch VGPR yet 18.8% occ) —
// so this round cuts issue count + hides B-load latency across barriers.
__global__ __launch_bounds__(256, 2) void multipole_main(
    const float* __restrict__ feat, const float* __restrict__ mu,
    const float* __restrict__ T0g, const float* __restrict__ T1g,
    const float* __restrict__ T2g, const float* __restrict__ T3g,
    const float* __restrict__ bq1, const float* __restrict__ bq2,
    const float* __restrict__ bs1, const float* __restrict__ bs2,
    const unsigned short* __restrict__ ws, float* __restrict__ out) {
  __shared__ unsigned short sXmain[TILE * 136];  // feat -> ms
  __shared__ unsigned short sXmain2[TILE * 136]; // H -> G (double buffer)
  __shared__ unsigned short sXmu[3][TILE * 136]; // mu channels -> mv channels
  __shared__ float sT[TILE][ST_STRIDE];          // per-node coeffs (see layout)

  const int t = threadIdx.x;
  const int lane = t & 63, wv = t >> 6;
  const int m = lane & 15, q = lane >> 4;
  const int cb = wv * 2;  // wave's col-tile base (cols [cb*16, cb*16+32))
  const int nodeBase = blockIdx.x * TILE;

  // ---- bias preloads (hide global latency under staging) ----
  const float bq1v0 = bq1[cb * 16 + m], bq1v1 = bq1[cb * 16 + 16 + m];
  const float bq2v0 = bq2[cb * 16 + m], bq2v1 = bq2[cb * 16 + 16 + m];
  const float bs1v0 = bs1[cb * 16 + m], bs1v1 = bs1[cb * 16 + 16 + m];
  const float bs2v0 = bs2[cb * 16 + m], bs2v1 = bs2[cb * 16 + 16 + m];

  // ---- feat tile -> sXmain (bf16), nt dwordx4 loads ----
  {
    int node = t >> 3, f0 = (t & 7) * 16;
    int gn = nodeBase + node;
    union { unsigned short u[16]; uint4 v[2]; } buf;
    if (gn < N_NODES) {
      const f32x4* p = (const f32x4*)(feat + (size_t)gn * 128 + f0);
      float xs[16];
#pragma unroll
      for (int i = 0; i < 4; ++i) *(f32x4*)(xs + 4 * i) = __builtin_nontemporal_load(p + i);
#pragma unroll
      for (int i = 0; i < 16; ++i) buf.u[i] = f2bf(xs[i]);
    } else {
#pragma unroll
      for (int i = 0; i < 16; ++i) buf.u[i] = 0;
    }
    uint4* dst = (uint4*)&sXmain[node * 136 + f0];
    dst[0] = buf.v[0]; dst[1] = buf.v[1];
  }

  // ---- mu tile -> sXmu[3] (bf16), nt vectorized ----
  {
    int node = t >> 3, f0 = (t & 7) * 16;
    int gn = nodeBase + node;
    union { unsigned short u[16]; uint4 v[2]; } b3[3];
    if (gn < N_NODES) {
      const f32x4* p = (const f32x4*)(mu + ((size_t)gn * 128 + f0) * 3);
      float xs[48];
#pragma unroll
      for (int i = 0; i < 12; ++i) *(f32x4*)(xs + 4 * i) = __builtin_nontemporal_load(p + i);
#pragma unroll
      for (int i = 0; i < 16; ++i) {
        b3[0].u[i] = f2bf(xs[i * 3 + 0]);
        b3[1].u[i] = f2bf(xs[i * 3 + 1]);
        b3[2].u[i] = f2bf(xs[i * 3 + 2]);
      }
    } else {
#pragma unroll
      for (int ch = 0; ch < 3; ++ch)
#pragma unroll
        for (int i = 0; i < 16; ++i) b3[ch].u[i] = 0;
    }
#pragma unroll
    for (int ch = 0; ch < 3; ++ch) {
      uint4* dst = (uint4*)&sXmu[ch][node * 136 + f0];
      dst[0] = b3[ch].v[0]; dst[1] = b3[ch].v[1];
    }
  }

  // ---- per-node T staging + symmetrization (threads 0..31, nt loads) ----
  if (t < TILE) {
    int n = nodeBase + t;
    bool val = n < N_NODES;
    float t0 = val ? __builtin_nontemporal_load(T0g + n) : 0.f;
    float t1[3], t2[9], t3[27];
#pragma unroll
    for (int i = 0; i < 3; ++i) t1[i] = val ? __builtin_nontemporal_load(T1g + n * 3 + i) : 0.f;
#pragma unroll
    for (int i = 0; i < 9; ++i) t2[i] = val ? __builtin_nontemporal_load(T2g + n * 9 + i) : 0.f;
#pragma unroll
    for (int i = 0; i < 27; ++i) t3[i] = val ? __builtin_nontemporal_load(T3g + n * 27 + i) : 0.f;
    float* Tr = sT[t];
    Tr[0] = t0;
    Tr[1] = t1[0]; Tr[2] = t1[1]; Tr[3] = t1[2];
#pragma unroll
    for (int i = 0; i < 9; ++i) Tr[4 + i] = t2[i];        // raw T2[i][j]
    // q2: pairs (00,01,02,11,12,22)
    Tr[16] = t2[0]; Tr[17] = t2[1] + t2[3]; Tr[18] = t2[2] + t2[6];
    Tr[19] = t2[4]; Tr[20] = t2[5] + t2[7]; Tr[21] = t2[8];
    // c3: multisets (000,001,002,011,012,022,111,112,122,222)
    Tr[24] = t3[0];
    Tr[25] = t3[1] + t3[3] + t3[9];
    Tr[26] = t3[2] + t3[6] + t3[18];
    Tr[27] = t3[4] + t3[10] + t3[12];
    Tr[28] = t3[5] + t3[7] + t3[11] + t3[15] + t3[19] + t3[21];
    Tr[29] = t3[8] + t3[20] + t3[24];
    Tr[30] = t3[13];
    Tr[31] = t3[14] + t3[16] + t3[22];
    Tr[32] = t3[17] + t3[23] + t3[25];
    Tr[33] = t3[26];
    // d3[i][pair]: sum_jk T3[i][j][k] vj vk, pairs (00,01,02,11,12,22)
#pragma unroll
    for (int i = 0; i < 3; ++i) {
      const float* b = t3 + 9 * i;
      float* d = Tr + 36 + 6 * i;
      d[0] = b[0]; d[1] = b[1] + b[3]; d[2] = b[2] + b[6];
      d[3] = b[4]; d[4] = b[5] + b[7]; d[5] = b[8];
    }
  }

  // prefetch S1's B while staging stores drain (in flight across B1)
  BF Bq1f = loadB8(ws, lane, cb);
  __syncthreads();  // B1: staging visible

  f32x4 A1[2][2], A2[2][2], A3[2][2];
  f32x2 msv[2][4];      // [rt][ri], .x = cc0, .y = cc1 (packed-FMA friendly)
  f32x2 mvv[3][2][4];

  // ---- S1: H = silu(feat@Wq1 + bq1) -> sXmain2 (no WAR barrier needed) ----
  gemm16p(sXmain, Bq1f, lane, A1);
  BF Bq2f = loadB8(ws + 1 * 16384, lane, cb);  // prefetch S2 B across B2
#pragma unroll
  for (int rt = 0; rt < 2; ++rt)
#pragma unroll
    for (int ri = 0; ri < 4; ++ri) {
      int lrow = rt * 16 + q * 4 + ri;
#pragma unroll
      for (int cc = 0; cc < 2; ++cc) {
        float h = fast_silu(A1[rt][cc][ri] + (cc ? bq1v1 : bq1v0));
        sXmain2[lrow * 136 + (cb + cc) * 16 + m] = f2bf(h);
      }
    }
  __syncthreads();  // B2: H ready

  // ---- S2: M0 = H@Wq2 + bq2 ; ms = T0*M0 ; mv_i = T1_i*M0 ----
  gemm16p(sXmain2, Bq2f, lane, A1);
  BF Bm1f = loadB8(ws + 2 * 16384, lane, cb);
  {
    const f32x2 bb = {bq2v0, bq2v1};
#pragma unroll
    for (int rt = 0; rt < 2; ++rt)
#pragma unroll
      for (int ri = 0; ri < 4; ++ri) {
        const f32x4 tv = ld4(sT[rt * 16 + q * 4 + ri]);
        f32x2 m0 = f32x2{A1[rt][0][ri], A1[rt][1][ri]} + bb;
        msv[rt][ri] = m0 * tv.x;
        mvv[0][rt][ri] = m0 * tv.y;
        mvv[1][rt][ri] = m0 * tv.z;
        mvv[2][rt][ri] = m0 * tv.w;
      }
  }

  // ---- M1 (shared B): ms += T1.M1 ; mv_i += T2[i][c]*M1c ----
  gemm3p(sXmu[0], sXmu[1], sXmu[2], Bm1f, lane, A1, A2, A3);
  BF Bm3f = loadB8(ws + 4 * 16384, lane, cb);
#pragma unroll
  for (int rt = 0; rt < 2; ++rt)
#pragma unroll
    for (int ri = 0; ri < 4; ++ri) {
      const float* Tr = sT[rt * 16 + q * 4 + ri];
      const f32x4 cA = ld4(Tr + 0), cB = ld4(Tr + 4), cC = ld4(Tr + 8), cD = ld4(Tr + 12);
      f32x2 v0 = {A1[rt][0][ri], A1[rt][1][ri]};
      f32x2 v1 = {A2[rt][0][ri], A2[rt][1][ri]};
      f32x2 v2 = {A3[rt][0][ri], A3[rt][1][ri]};
      msv[rt][ri]    += v0 * cA.y + v1 * cA.z + v2 * cA.w;
      mvv[0][rt][ri] += v0 * cB.x + v1 * cB.y + v2 * cB.z;
      mvv[1][rt][ri] += v0 * cB.w + v1 * cC.x + v2 * cC.y;
      mvv[2][rt][ri] += v0 * cC.z + v1 * cC.w + v2 * cD.x;
    }

  // ---- M3 channels (shared B) then cubic: ms += c3[ijk] u_i u_j u_k ----
  gemm3p(sXmu[0], sXmu[1], sXmu[2], Bm3f, lane, A1, A2, A3);
  BF Bm2f = loadB8(ws + 3 * 16384, lane, cb);
#pragma unroll
  for (int rt = 0; rt < 2; ++rt)
#pragma unroll
    for (int ri = 0; ri < 4; ++ri) {
      const float* Tr = sT[rt * 16 + q * 4 + ri];
      const f32x4 E = ld4(Tr + 24), F = ld4(Tr + 28), Gv = ld4(Tr + 32);
      f32x2 u0 = {A1[rt][0][ri], A1[rt][1][ri]};
      f32x2 u1 = {A2[rt][0][ri], A2[rt][1][ri]};
      f32x2 u2 = {A3[rt][0][ri], A3[rt][1][ri]};
      f32x2 Q0 = u0 * u0, Q1 = u0 * u1, Q2 = u0 * u2;
      f32x2 Q3 = u1 * u1, Q4 = u1 * u2, Q5 = u2 * u2;
      msv[rt][ri] += (Q0 * u0) * E.x + (Q0 * u1) * E.y + (Q0 * u2) * E.z +
                     (Q1 * u1) * E.w + (Q1 * u2) * F.x + (Q2 * u2) * F.y +
                     (Q3 * u1) * F.z + (Q3 * u2) * F.w + (Q4 * u2) * Gv.x +
                     (Q5 * u2) * Gv.y;
    }

  // ---- M2 channels (shared B) then quadratic: ms += q2:PP ; mv += d3:PP ----
  gemm3p(sXmu[0], sXmu[1], sXmu[2], Bm2f, lane, A1, A2, A3);
  BF Bs1f = loadB8(ws + 5 * 16384, lane, cb);  // prefetch Ws1 across B3/B4
#pragma unroll
  for (int rt = 0; rt < 2; ++rt)
#pragma unroll
    for (int ri = 0; ri < 4; ++ri) {
      const float* Tr = sT[rt * 16 + q * 4 + ri];
      const f32x4 H4 = ld4(Tr + 16), I4 = ld4(Tr + 20);
      const f32x4 J = ld4(Tr + 36), K = ld4(Tr + 40), L = ld4(Tr + 44);
      const f32x4 M4 = ld4(Tr + 48), N4 = ld4(Tr + 52);
      f32x2 v0 = {A1[rt][0][ri], A1[rt][1][ri]};
      f32x2 v1 = {A2[rt][0][ri], A2[rt][1][ri]};
      f32x2 v2 = {A3[rt][0][ri], A3[rt][1][ri]};
      f32x2 P0 = v0 * v0, P1 = v0 * v1, P2 = v0 * v2;
      f32x2 P3 = v1 * v1, P4 = v1 * v2, P5 = v2 * v2;
      msv[rt][ri]    += P0 * H4.x + P1 * H4.y + P2 * H4.z + P3 * H4.w + P4 * I4.x + P5 * I4.y;
      mvv[0][rt][ri] += P0 * J.x + P1 * J.y + P2 * J.z + P3 * J.w + P4 * K.x + P5 * K.y;
      mvv[1][rt][ri] += P0 * K.z + P1 * K.w + P2 * L.x + P3 * L.y + P4 * L.z + P5 * L.w;
      mvv[2][rt][ri] += P0 * M4.x + P1 * M4.y + P2 * M4.z + P3 * M4.w + P4 * N4.x + P5 * N4.y;
    }
  __syncthreads();  // B3: all waves done reading mu tiles (and feat long ago)

  // ---- flush ms -> sXmain (feat dead), mv -> sXmu (bf16, A-operand) ----
#pragma unroll
  for (int rt = 0; rt < 2; ++rt)
#pragma unroll
    for (int ri = 0; ri < 4; ++ri) {
      int lrow = rt * 16 + q * 4 + ri;
      int col0 = cb * 16 + m, col1 = col0 + 16;
      sXmain[lrow * 136 + col0] = f2bf(msv[rt][ri].x);
      sXmain[lrow * 136 + col1] = f2bf(msv[rt][ri].y);
      sXmu[0][lrow * 136 + col0] = f2bf(mvv[0][rt][ri].x);
      sXmu[0][lrow * 136 + col1] = f2bf(mvv[0][rt][ri].y);
      sXmu[1][lrow * 136 + col0] = f2bf(mvv[1][rt][ri].x);
      sXmu[1][lrow * 136 + col1] = f2bf(mvv[1][rt][ri].y);
      sXmu[2][lrow * 136 + col0] = f2bf(mvv[2][rt][ri].x);
      sXmu[2][lrow * 136 + col1] = f2bf(mvv[2][rt][ri].y);
    }
  __syncthreads();  // B4: ms/mv tiles ready

  // ---- S12: G = silu(ms@Ws1 + bs1) -> sXmain2 (H dead, no WAR barrier) ----
  gemm16p(sXmain, Bs1f, lane, A1);
  BF Bs2f = loadB8(ws + 6 * 16384, lane, cb);  // prefetch Ws2 across B5
#pragma unroll
  for (int rt = 0; rt < 2; ++rt)
#pragma unroll
    for (int ri = 0; ri < 4; ++ri) {
      int lrow = rt * 16 + q * 4 + ri;
#pragma unroll
      for (int cc = 0; cc < 2; ++cc) {
        float g = fast_silu(A1[rt][cc][ri] + (cc ? bs1v1 : bs1v0));
        sXmain2[lrow * 136 + (cb + cc) * 16 + m] = f2bf(g);
      }
    }
  __syncthreads();  // B5: G ready

  // ---- S13: ms_out = G@Ws2 + bs2 -> out[0 : N*128] (nt stores) ----
  gemm16p(sXmain2, Bs2f, lane, A1);
  BF Bvf = loadB8(ws + 7 * 16384, lane, cb);  // Wv B issues under the stores
#pragma unroll
  for (int rt = 0; rt < 2; ++rt)
#pragma unroll
    for (int ri = 0; ri < 4; ++ri) {
      int grow = nodeBase + rt * 16 + q * 4 + ri;
      if (grow < N_NODES) {
#pragma unroll
        for (int cc = 0; cc < 2; ++cc) {
          int col = (cb + cc) * 16 + m;
          __builtin_nontemporal_store(A1[rt][cc][ri] + (cc ? bs2v1 : bs2v0),
                                      out + (size_t)grow * 128 + col);
        }
      }
    }

  // ---- S14-16: mv_out = mv_ch @ Wv, 3 channels together: 12B/lane stores ----
  float* out2 = out + (size_t)N_NODES * 128;
  gemm3p(sXmu[0], sXmu[1], sXmu[2], Bvf, lane, A1, A2, A3);
#pragma unroll
  for (int rt = 0; rt < 2; ++rt)
#pragma unroll
    for (int ri = 0; ri < 4; ++ri) {
      int grow = nodeBase + rt * 16 + q * 4 + ri;
      if (grow < N_NODES) {
#pragma unroll
        for (int cc = 0; cc < 2; ++cc) {
          int col = (cb + cc) * 16 + m;
          float* p = out2 + ((size_t)grow * 128 + col) * 3;
          __builtin_nontemporal_store(A1[rt][cc][ri], p + 0);
          __builtin_nontemporal_store(A2[rt][cc][ri], p + 1);
          __builtin_nontemporal_store(A3[rt][cc][ri], p + 2);
        }
      }
    }
}

extern "C" void kernel_launch(void* const* d_in, const int* in_sizes, int n_in,
                              void* d_out, int out_size, void* d_ws, size_t ws_size,
                              hipStream_t stream) {
  const float* feat = (const float*)d_in[0];
  const float* mu   = (const float*)d_in[1];
  const float* T0   = (const float*)d_in[2];
  const float* T1   = (const float*)d_in[3];
  const float* T2   = (const float*)d_in[4];
  const float* T3   = (const float*)d_in[5];
  const float* Wq1  = (const float*)d_in[6];
  const float* bq1  = (const float*)d_in[7];
  const float* Wq2  = (const float*)d_in[8];
  const float* bq2  = (const float*)d_in[9];
  const float* WT1  = (const float*)d_in[10];
  const float* WT2  = (const float*)d_in[11];
  const float* WT3  = (const float*)d_in[12];
  const float* Ws1  = (const float*)d_in[13];
  const float* bs1  = (const float*)d_in[14];
  const float* Ws2  = (const float*)d_in[15];
  const float* bs2  = (const float*)d_in[16];
  const float* Wv   = (const float*)d_in[17];
  unsigned short* ws = (unsigned short*)d_ws;  // needs 8*128*128*2 = 256 KB
  float* out = (float*)d_out;

  prep_weights<<<64, 256, 0, stream>>>(Wq1, Wq2, WT1, WT2, WT3, Ws1, Ws2, Wv, ws);
  multipole_main<<<NBLK, 256, 0, stream>>>(feat, mu, T0, T1, T2, T3,
                                           bq1, bq2, bs1, bs2, ws, out);
}

// Round 8
// 272.076 us; speedup vs baseline: 1.1258x; 1.1258x over previous
//
#include <hip/hip_runtime.h>
#include <cstdint>

#define N_NODES 50000
#define TILE 32
#define NBLK ((N_NODES + TILE - 1) / TILE)  // 1563

// fragment / accumulator vector types (gfx950 mfma bf16 builtins take v8 bf16)
typedef __bf16 bf16x8 __attribute__((ext_vector_type(8)));
typedef unsigned short ushort8_t __attribute__((ext_vector_type(8)));
typedef float f32x4 __attribute__((ext_vector_type(4)));

__device__ __forceinline__ unsigned short f2bf(float x) {
  return __builtin_bit_cast(unsigned short, (__bf16)x);  // native RNE v_cvt
}

__device__ __forceinline__ float fast_silu(float x) {
  return x / (1.0f + __expf(-x));
}

// ---------------------------------------------------------------------------
// Prologue: shuffle all 8 weight matrices (fp32 [f][g], 128x128) into
// B-fragment-ordered bf16 atoms in d_ws.
// Atom (c in 0..7 coltile, kt in 0..3 kstep, lane in 0..63) holds 8 bf16:
//   W[k0+j][g],  g = (lane&15)+16c,  k0 = 32kt + (lane>>4)*8,  j=0..7
// so the main kernel's B-frag load is simply ds_read_b128 at atom*16.
// ---------------------------------------------------------------------------
__global__ __launch_bounds__(256) void prep_weights(
    const float* __restrict__ Wq1, const float* __restrict__ Wq2,
    const float* __restrict__ WT1, const float* __restrict__ WT2,
    const float* __restrict__ WT3, const float* __restrict__ Ws1,
    const float* __restrict__ Ws2, const float* __restrict__ Wv,
    unsigned short* __restrict__ ws) {
  int tid = blockIdx.x * 256 + threadIdx.x;
  int w = tid >> 11;          // which weight (0..7), 2048 atoms each
  int rest = tid & 2047;      // atom index = (c*4+kt)*64 + lane
  int c = rest >> 8;
  int kt = (rest >> 6) & 3;
  int lane = rest & 63;
  int g = (lane & 15) + 16 * c;
  int k0 = kt * 32 + (lane >> 4) * 8;
  const float* srcs[8] = {Wq1, Wq2, WT1, WT2, WT3, Ws1, Ws2, Wv};
  const float* src = srcs[w];
  union { unsigned short u[8]; uint4 v; } o;
#pragma unroll
  for (int j = 0; j < 8; ++j) o.u[j] = f2bf(src[(k0 + j) * 128 + g]);
  *(uint4*)(ws + (size_t)w * 16384 + (size_t)rest * 8) = o.v;
}

// ---------------------------------------------------------------------------
// GEMM: Y[32 x 128] = A[32 x 128] @ W[128 x 128] on one block (4 waves).
// Wave owns rows 0..31 x cols [32*wv, 32*wv+32): 2x2 tiles of 16x16.
// sA: bf16, row stride 136 (pad +8 breaks b128 bank conflicts).
// sWp: frag-ordered atoms in LDS (see prep_weights). [R0 structure, verbatim]
// ---------------------------------------------------------------------------
__device__ __forceinline__ void gemm16(const unsigned short* sA,
                                       const unsigned short* sWp,
                                       int lane, int cb, f32x4 acc[2][2]) {
  const int m = lane & 15, q = lane >> 4;
  const f32x4 vzero = {0.f, 0.f, 0.f, 0.f};
#pragma unroll
  for (int rt = 0; rt < 2; ++rt)
#pragma unroll
    for (int cc = 0; cc < 2; ++cc) acc[rt][cc] = vzero;
#pragma unroll
  for (int kt = 0; kt < 4; ++kt) {
    const int k0 = q * 8 + kt * 32;
    bf16x8 a0 = __builtin_bit_cast(bf16x8, *(const ushort8_t*)(sA + m * 136 + k0));
    bf16x8 a1 = __builtin_bit_cast(bf16x8, *(const ushort8_t*)(sA + (m + 16) * 136 + k0));
#pragma unroll
    for (int cc = 0; cc < 2; ++cc) {
      bf16x8 b = __builtin_bit_cast(
          bf16x8, *(const ushort8_t*)(sWp + (((cb + cc) * 4 + kt) * 64 + lane) * 8));
      acc[0][cc] = __builtin_amdgcn_mfma_f32_16x16x32_bf16(a0, b, acc[0][cc], 0, 0, 0);
      acc[1][cc] = __builtin_amdgcn_mfma_f32_16x16x32_bf16(a1, b, acc[1][cc], 0, 0, 0);
    }
  }
}

// 3-channel GEMM sharing the B fragments read from sW LDS: one ds_read of B
// feeds all 3 channels (LDS-B analog of the R2-passed gemm3g). Used for
// M1/M3/M2 and the Wv epilogue — B ds_read traffic /3 in those stages.
__device__ __forceinline__ void gemm3L(const unsigned short* s0,
                                       const unsigned short* s1,
                                       const unsigned short* s2,
                                       const unsigned short* sWp,
                                       int lane, int cb,
                                       f32x4 A1[2][2], f32x4 A2[2][2],
                                       f32x4 A3[2][2]) {
  const int m = lane & 15, q = lane >> 4;
  const f32x4 vzero = {0.f, 0.f, 0.f, 0.f};
#pragma unroll
  for (int rt = 0; rt < 2; ++rt)
#pragma unroll
    for (int cc = 0; cc < 2; ++cc) {
      A1[rt][cc] = vzero; A2[rt][cc] = vzero; A3[rt][cc] = vzero;
    }
#pragma unroll
  for (int kt = 0; kt < 4; ++kt) {
    const int k0 = q * 8 + kt * 32;
    bf16x8 a00 = __builtin_bit_cast(bf16x8, *(const ushort8_t*)(s0 + m * 136 + k0));
    bf16x8 a01 = __builtin_bit_cast(bf16x8, *(const ushort8_t*)(s0 + (m + 16) * 136 + k0));
    bf16x8 a10 = __builtin_bit_cast(bf16x8, *(const ushort8_t*)(s1 + m * 136 + k0));
    bf16x8 a11 = __builtin_bit_cast(bf16x8, *(const ushort8_t*)(s1 + (m + 16) * 136 + k0));
    bf16x8 a20 = __builtin_bit_cast(bf16x8, *(const ushort8_t*)(s2 + m * 136 + k0));
    bf16x8 a21 = __builtin_bit_cast(bf16x8, *(const ushort8_t*)(s2 + (m + 16) * 136 + k0));
#pragma unroll
    for (int cc = 0; cc < 2; ++cc) {
      bf16x8 b = __builtin_bit_cast(
          bf16x8, *(const ushort8_t*)(sWp + (((cb + cc) * 4 + kt) * 64 + lane) * 8));
      A1[0][cc] = __builtin_amdgcn_mfma_f32_16x16x32_bf16(a00, b, A1[0][cc], 0, 0, 0);
      A1[1][cc] = __builtin_amdgcn_mfma_f32_16x16x32_bf16(a01, b, A1[1][cc], 0, 0, 0);
      A2[0][cc] = __builtin_amdgcn_mfma_f32_16x16x32_bf16(a10, b, A2[0][cc], 0, 0, 0);
      A2[1][cc] = __builtin_amdgcn_mfma_f32_16x16x32_bf16(a11, b, A2[1][cc], 0, 0, 0);
      A3[0][cc] = __builtin_amdgcn_mfma_f32_16x16x32_bf16(a20, b, A3[0][cc], 0, 0, 0);
      A3[1][cc] = __builtin_amdgcn_mfma_f32_16x16x32_bf16(a21, b, A3[1][cc], 0, 0, 0);
    }
  }
}

// ---------------------------------------------------------------------------
// Fused main kernel: one block = 32 nodes, full pipeline.
// STRUCTURE = R0 VERBATIM (graded-best 275.8us): sW LDS weight staging,
// same barrier chain, plain (non-nt) loads/stores, __launch_bounds__(256,2).
// Session evidence: direct-from-L2 B reads cut the main dispatch 166->138us
// but grew per-iteration overhead by ~50us (graded 275.8 -> 300+), and the
// TLP restructure failed correctness 3x. This round grafts ONLY
// passing-proven in-dispatch fixes onto R0: native f2bf, vectorized staging
// loads, shared-B gemm3L for M1/M3/M2/Wv, contiguous mv_out stores.
// ---------------------------------------------------------------------------
__global__ __launch_bounds__(256, 2) void multipole_main(
    const float* __restrict__ feat, const float* __restrict__ mu,
    const float* __restrict__ T0g, const float* __restrict__ T1g,
    const float* __restrict__ T2g, const float* __restrict__ T3g,
    const float* __restrict__ bq1, const float* __restrict__ bq2,
    const float* __restrict__ bs1, const float* __restrict__ bs2,
    const unsigned short* __restrict__ ws, float* __restrict__ out) {
  __shared__ unsigned short sW[16384];          // 32 KB: current weight (frag-ordered)
  __shared__ unsigned short sXmain[TILE * 136]; // feat -> H -> ms -> G
  __shared__ unsigned short sXmu[3][TILE * 136];// mu channels, later mv channels
  __shared__ float sT[TILE][49];                // per-node T0/T1/T2raw/sym coeffs

  const int t = threadIdx.x;
  const int lane = t & 63, wv = t >> 6;
  const int m = lane & 15, q = lane >> 4;
  const int cb = wv * 2;  // wave's col-tile base (cols [cb*16, cb*16+32))
  const int nodeBase = blockIdx.x * TILE;

  auto stage_w = [&](int slot) {
    const uint4* src = (const uint4*)(ws + (size_t)slot * 16384);
    uint4* dst = (uint4*)sW;
#pragma unroll
    for (int i = 0; i < 8; ++i) dst[t + i * 256] = src[t + i * 256];
  };

  // ---- per-node T staging + symmetrization (threads 0..31) ----
  if (t < TILE) {
    int n = nodeBase + t;
    bool val = n < N_NODES;
    float t0 = val ? T0g[n] : 0.f;
    float t1[3], t2[9], t3[27];
#pragma unroll
    for (int i = 0; i < 3; ++i) t1[i] = val ? T1g[n * 3 + i] : 0.f;
#pragma unroll
    for (int i = 0; i < 9; ++i) t2[i] = val ? T2g[n * 9 + i] : 0.f;
#pragma unroll
    for (int i = 0; i < 27; ++i) t3[i] = val ? T3g[n * 27 + i] : 0.f;
    float* Tr = sT[t];
    Tr[0] = t0;
    Tr[1] = t1[0]; Tr[2] = t1[1]; Tr[3] = t1[2];
#pragma unroll
    for (int i = 0; i < 9; ++i) Tr[4 + i] = t2[i];        // raw T2[i][j]
    // q2: pairs (00,01,02,11,12,22) for sum_ij T2ij vi vj
    Tr[13] = t2[0]; Tr[14] = t2[1] + t2[3]; Tr[15] = t2[2] + t2[6];
    Tr[16] = t2[4]; Tr[17] = t2[5] + t2[7]; Tr[18] = t2[8];
    // c3: multisets (000,001,002,011,012,022,111,112,122,222)
    Tr[19] = t3[0];
    Tr[20] = t3[1] + t3[3] + t3[9];
    Tr[21] = t3[2] + t3[6] + t3[18];
    Tr[22] = t3[4] + t3[10] + t3[12];
    Tr[23] = t3[5] + t3[7] + t3[11] + t3[15] + t3[19] + t3[21];
    Tr[24] = t3[8] + t3[20] + t3[24];
    Tr[25] = t3[13];
    Tr[26] = t3[14] + t3[16] + t3[22];
    Tr[27] = t3[17] + t3[23] + t3[25];
    Tr[28] = t3[26];
    // d3[i][pair]: sum_jk T3[i][j][k] vj vk, pairs (00,01,02,11,12,22)
#pragma unroll
    for (int i = 0; i < 3; ++i) {
      const float* b = t3 + 9 * i;
      float* d = Tr + 29 + 6 * i;
      d[0] = b[0]; d[1] = b[1] + b[3]; d[2] = b[2] + b[6];
      d[3] = b[4]; d[4] = b[5] + b[7]; d[5] = b[8];
    }
  }

  // ---- feat tile -> sXmain (bf16), vectorized dwordx4 loads ----
  {
    int node = t >> 3, f0 = (t & 7) * 16;
    int gn = nodeBase + node;
    union { unsigned short u[16]; uint4 v[2]; } buf;
    if (gn < N_NODES) {
      const float4* p = (const float4*)(feat + (size_t)gn * 128 + f0);
      float xs[16];
#pragma unroll
      for (int i = 0; i < 4; ++i) *(float4*)(xs + 4 * i) = p[i];
#pragma unroll
      for (int i = 0; i < 16; ++i) buf.u[i] = f2bf(xs[i]);
    } else {
#pragma unroll
      for (int i = 0; i < 16; ++i) buf.u[i] = 0;
    }
    uint4* dst = (uint4*)&sXmain[node * 136 + f0];
    dst[0] = buf.v[0]; dst[1] = buf.v[1];
  }
  stage_w(0);  // Wq1
  __syncthreads();

  f32x4 A1[2][2], A2[2][2], A3[2][2];
  float msv[2][2][4];
  float mvv[3][2][2][4];

  // ---- S1: H = silu(feat@Wq1 + bq1) ----
  gemm16(sXmain, sW, lane, cb, A1);
  float b0 = bq1[cb * 16 + m], b1 = bq1[cb * 16 + 16 + m];
  __syncthreads();
#pragma unroll
  for (int rt = 0; rt < 2; ++rt)
#pragma unroll
    for (int ri = 0; ri < 4; ++ri) {
      int lrow = rt * 16 + q * 4 + ri;
#pragma unroll
      for (int cc = 0; cc < 2; ++cc) {
        float h = fast_silu(A1[rt][cc][ri] + (cc ? b1 : b0));
        sXmain[lrow * 136 + (cb + cc) * 16 + m] = f2bf(h);
      }
    }
  stage_w(1);  // Wq2
  __syncthreads();

  // ---- S2: M0 = H@Wq2 + bq2 ; ms = T0*M0 ; mv_i = T1_i*M0 ----
  gemm16(sXmain, sW, lane, cb, A1);
  {
    float bb0 = bq2[cb * 16 + m], bb1 = bq2[cb * 16 + 16 + m];
#pragma unroll
    for (int rt = 0; rt < 2; ++rt)
#pragma unroll
      for (int ri = 0; ri < 4; ++ri) {
        const float* Tr = sT[rt * 16 + q * 4 + ri];
        float t0 = Tr[0], ta = Tr[1], tb = Tr[2], tc = Tr[3];
#pragma unroll
        for (int cc = 0; cc < 2; ++cc) {
          float m0 = A1[rt][cc][ri] + (cc ? bb1 : bb0);
          msv[rt][cc][ri] = t0 * m0;
          mvv[0][rt][cc][ri] = ta * m0;
          mvv[1][rt][cc][ri] = tb * m0;
          mvv[2][rt][cc][ri] = tc * m0;
        }
      }
  }
  __syncthreads();

  // ---- mu tile -> sXmu[3] (bf16), vectorized dwordx4 loads + WT1 ----
  {
    int node = t >> 3, f0 = (t & 7) * 16;
    int gn = nodeBase + node;
    union { unsigned short u[16]; uint4 v[2]; } b3[3];
    if (gn < N_NODES) {
      const float4* p = (const float4*)(mu + ((size_t)gn * 128 + f0) * 3);
      float xs[48];
#pragma unroll
      for (int i = 0; i < 12; ++i) *(float4*)(xs + 4 * i) = p[i];
#pragma unroll
      for (int i = 0; i < 16; ++i) {
        b3[0].u[i] = f2bf(xs[i * 3 + 0]);
        b3[1].u[i] = f2bf(xs[i * 3 + 1]);
        b3[2].u[i] = f2bf(xs[i * 3 + 2]);
      }
    } else {
#pragma unroll
      for (int ch = 0; ch < 3; ++ch)
#pragma unroll
        for (int i = 0; i < 16; ++i) b3[ch].u[i] = 0;
    }
#pragma unroll
    for (int ch = 0; ch < 3; ++ch) {
      uint4* dst = (uint4*)&sXmu[ch][node * 136 + f0];
      dst[0] = b3[ch].v[0]; dst[1] = b3[ch].v[1];
    }
  }
  stage_w(2);  // WT1
  __syncthreads();

  // ---- M1 (shared B): ms += T1.M1 ; mv_i += T2[i][c]*M1c ----
  gemm3L(sXmu[0], sXmu[1], sXmu[2], sW, lane, cb, A1, A2, A3);
#pragma unroll
  for (int rt = 0; rt < 2; ++rt)
#pragma unroll
    for (int ri = 0; ri < 4; ++ri) {
      const float* Tr = sT[rt * 16 + q * 4 + ri];
#pragma unroll
      for (int cc = 0; cc < 2; ++cc) {
        float v0 = A1[rt][cc][ri], v1 = A2[rt][cc][ri], v2 = A3[rt][cc][ri];
        msv[rt][cc][ri] += Tr[1] * v0 + Tr[2] * v1 + Tr[3] * v2;
        mvv[0][rt][cc][ri] += Tr[4] * v0 + Tr[5] * v1 + Tr[6] * v2;
        mvv[1][rt][cc][ri] += Tr[7] * v0 + Tr[8] * v1 + Tr[9] * v2;
        mvv[2][rt][cc][ri] += Tr[10] * v0 + Tr[11] * v1 + Tr[12] * v2;
      }
    }
  __syncthreads();
  stage_w(4);  // WT3
  __syncthreads();

  // ---- M3 channels (shared B) then cubic: ms += sum c3[ijk] u_i u_j u_k ----
  gemm3L(sXmu[0], sXmu[1], sXmu[2], sW, lane, cb, A1, A2, A3);
#pragma unroll
  for (int rt = 0; rt < 2; ++rt)
#pragma unroll
    for (int ri = 0; ri < 4; ++ri) {
      const float* Cp = sT[rt * 16 + q * 4 + ri] + 19;
      float c0 = Cp[0], c1 = Cp[1], c2 = Cp[2], c3 = Cp[3], c4 = Cp[4];
      float c5 = Cp[5], c6 = Cp[6], c7 = Cp[7], c8 = Cp[8], c9 = Cp[9];
#pragma unroll
      for (int cc = 0; cc < 2; ++cc) {
        float u0 = A1[rt][cc][ri], u1 = A2[rt][cc][ri], u2 = A3[rt][cc][ri];
        float Q0 = u0 * u0, Q1 = u0 * u1, Q2 = u0 * u2;
        float Q3 = u1 * u1, Q4 = u1 * u2, Q5 = u2 * u2;
        msv[rt][cc][ri] += c0 * (Q0 * u0) + c1 * (Q0 * u1) + c2 * (Q0 * u2) +
                           c3 * (Q1 * u1) + c4 * (Q1 * u2) + c5 * (Q2 * u2) +
                           c6 * (Q3 * u1) + c7 * (Q3 * u2) + c8 * (Q4 * u2) +
                           c9 * (Q5 * u2);
      }
    }
  __syncthreads();
  stage_w(3);  // WT2
  __syncthreads();

  // ---- M2 channels (shared B) then quadratic: ms += q2:PP ; mv_i += d3_i:PP ----
  gemm3L(sXmu[0], sXmu[1], sXmu[2], sW, lane, cb, A1, A2, A3);
#pragma unroll
  for (int rt = 0; rt < 2; ++rt)
#pragma unroll
    for (int ri = 0; ri < 4; ++ri) {
      const float* Tr = sT[rt * 16 + q * 4 + ri];
      const float* q2 = Tr + 13;
      const float* d3 = Tr + 29;
      float q20 = q2[0], q21 = q2[1], q22 = q2[2], q23 = q2[3], q24 = q2[4], q25 = q2[5];
#pragma unroll
      for (int cc = 0; cc < 2; ++cc) {
        float v0 = A1[rt][cc][ri], v1 = A2[rt][cc][ri], v2 = A3[rt][cc][ri];
        float P0 = v0 * v0, P1 = v0 * v1, P2 = v0 * v2;
        float P3 = v1 * v1, P4 = v1 * v2, P5 = v2 * v2;
        msv[rt][cc][ri] += q20 * P0 + q21 * P1 + q22 * P2 + q23 * P3 + q24 * P4 + q25 * P5;
        mvv[0][rt][cc][ri] += d3[0] * P0 + d3[1] * P1 + d3[2] * P2 + d3[3] * P3 + d3[4] * P4 + d3[5] * P5;
        mvv[1][rt][cc][ri] += d3[6] * P0 + d3[7] * P1 + d3[8] * P2 + d3[9] * P3 + d3[10] * P4 + d3[11] * P5;
        mvv[2][rt][cc][ri] += d3[12] * P0 + d3[13] * P1 + d3[14] * P2 + d3[15] * P3 + d3[16] * P4 + d3[17] * P5;
      }
    }
  __syncthreads();

  // ---- flush ms -> sXmain, mv -> sXmu (bf16, A-operand layout) ----
#pragma unroll
  for (int rt = 0; rt < 2; ++rt)
#pragma unroll
    for (int ri = 0; ri < 4; ++ri) {
      int lrow = rt * 16 + q * 4 + ri;
#pragma unroll
      for (int cc = 0; cc < 2; ++cc) {
        int col = (cb + cc) * 16 + m;
        sXmain[lrow * 136 + col] = f2bf(msv[rt][cc][ri]);
        sXmu[0][lrow * 136 + col] = f2bf(mvv[0][rt][cc][ri]);
        sXmu[1][lrow * 136 + col] = f2bf(mvv[1][rt][cc][ri]);
        sXmu[2][lrow * 136 + col] = f2bf(mvv[2][rt][cc][ri]);
      }
    }
  stage_w(5);  // Ws1
  __syncthreads();

  // ---- S12: G = silu(ms@Ws1 + bs1) ----
  gemm16(sXmain, sW, lane, cb, A1);
  {
    float s0 = bs1[cb * 16 + m], s1 = bs1[cb * 16 + 16 + m];
    __syncthreads();
#pragma unroll
    for (int rt = 0; rt < 2; ++rt)
#pragma unroll
      for (int ri = 0; ri < 4; ++ri) {
        int lrow = rt * 16 + q * 4 + ri;
#pragma unroll
        for (int cc = 0; cc < 2; ++cc) {
          float g = fast_silu(A1[rt][cc][ri] + (cc ? s1 : s0));
          sXmain[lrow * 136 + (cb + cc) * 16 + m] = f2bf(g);
        }
      }
  }
  stage_w(6);  // Ws2
  __syncthreads();

  // ---- S13: ms_out = G@Ws2 + bs2 -> out[0 : N*128] ----
  gemm16(sXmain, sW, lane, cb, A1);
  {
    float s0 = bs2[cb * 16 + m], s1 = bs2[cb * 16 + 16 + m];
#pragma unroll
    for (int rt = 0; rt < 2; ++rt)
#pragma unroll
      for (int ri = 0; ri < 4; ++ri) {
        int grow = nodeBase + rt * 16 + q * 4 + ri;
        if (grow < N_NODES) {
#pragma unroll
          for (int cc = 0; cc < 2; ++cc) {
            int col = (cb + cc) * 16 + m;
            out[(size_t)grow * 128 + col] = A1[rt][cc][ri] + (cc ? s1 : s0);
          }
        }
      }
  }
  __syncthreads();
  stage_w(7);  // Wv
  __syncthreads();

  // ---- S14-16: mv_out = mv_ch @ Wv, all 3 channels together (shared B):
  // each lane stores 12 contiguous bytes -> dense lines, single pass ----
  float* out2 = out + (size_t)N_NODES * 128;
  gemm3L(sXmu[0], sXmu[1], sXmu[2], sW, lane, cb, A1, A2, A3);
#pragma unroll
  for (int rt = 0; rt < 2; ++rt)
#pragma unroll
    for (int ri = 0; ri < 4; ++ri) {
      int grow = nodeBase + rt * 16 + q * 4 + ri;
      if (grow < N_NODES) {
#pragma unroll
        for (int cc = 0; cc < 2; ++cc) {
          int col = (cb + cc) * 16 + m;
          float* p = out2 + ((size_t)grow * 128 + col) * 3;
          p[0] = A1[rt][cc][ri];
          p[1] = A2[rt][cc][ri];
          p[2] = A3[rt][cc][ri];
        }
      }
    }
}

extern "C" void kernel_launch(void* const* d_in, const int* in_sizes, int n_in,
                              void* d_out, int out_size, void* d_ws, size_t ws_size,
                              hipStream_t stream) {
  const float* feat = (const float*)d_in[0];
  const float* mu   = (const float*)d_in[1];
  const float* T0   = (const float*)d_in[2];
  const float* T1   = (const float*)d_in[3];
  const float* T2   = (const float*)d_in[4];
  const float* T3   = (const float*)d_in[5];
  const float* Wq1  = (const float*)d_in[6];
  const float* bq1  = (const float*)d_in[7];
  const float* Wq2  = (const float*)d_in[8];
  const float* bq2  = (const float*)d_in[9];
  const float* WT1  = (const float*)d_in[10];
  const float* WT2  = (const float*)d_in[11];
  const float* WT3  = (const float*)d_in[12];
  const float* Ws1  = (const float*)d_in[13];
  const float* bs1  = (const float*)d_in[14];
  const float* Ws2  = (const float*)d_in[15];
  const float* bs2  = (const float*)d_in[16];
  const float* Wv   = (const float*)d_in[17];
  unsigned short* ws = (unsigned short*)d_ws;  // needs 8*128*128*2 = 256 KB
  float* out = (float*)d_out;

  prep_weights<<<64, 256, 0, stream>>>(Wq1, Wq2, WT1, WT2, WT3, Ws1, Ws2, Wv, ws);
  multipole_main<<<NBLK, 256, 0, stream>>>(feat, mu, T0, T1, T2, T3,
                                           bq1, bq2, bs1, bs2, ws, out);
}